// Round 10
// baseline (475.112 us; speedup 1.0000x reference)
//
#include <hip/hip_runtime.h>
#include <hip/hip_bf16.h>
#include <hip/hip_fp16.h>

#define D 128
#define BSH 7                  // CSR bucket shift: 128 destinations per bucket
#define NBLK 128               // binning blocks per side
typedef unsigned short u16;
typedef unsigned int u32;
typedef __attribute__((ext_vector_type(4))) unsigned int u32x4;
typedef _Float16 f16;
typedef __attribute__((ext_vector_type(2))) _Float16 h2t;
typedef __attribute__((ext_vector_type(8))) _Float16 f16x8;
typedef __attribute__((ext_vector_type(4))) float f32x4;

__device__ __forceinline__ float bf2f(u16 u) {
    return __uint_as_float(((u32)u) << 16);
}
__device__ __forceinline__ u16 f2bf(float f) {
    union { float f; u32 u; } a; a.f = f;
    u32 r = (a.u + 0x7FFF + ((a.u >> 16) & 1)) >> 16;   // RNE
    return (u16)r;
}
// fp16 helpers (internal canonical dtype — packed math + dot2 on CDNA4)
__device__ __forceinline__ u16 f2h(float f) {
    union { f16 h; u16 u; } c; c.h = (f16)f; return c.u;
}
__device__ __forceinline__ h2t u2h2(u32 v) {
    union { u32 u; h2t h; } c; c.u = v; return c.h;
}
__device__ __forceinline__ u32 h22u(h2t h) {
    union { h2t h; u32 u; } c; c.h = h; return c.u;
}
__device__ __forceinline__ float2 h2f2(u32 v) {
    h2t h = u2h2(v);
    return make_float2((float)h[0], (float)h[1]);
}
__device__ __forceinline__ u32 packh2(float a, float b) {
    union { h2t h; u32 u; } c; c.h[0] = (f16)a; c.h[1] = (f16)b; return c.u;
}
// flag-dependent raw-input access (epilogue / prep only)
__device__ __forceinline__ float ldIn(const void* p, size_t i, int isBf) {
    return isBf ? bf2f(((const u16*)p)[i]) : ((const float*)p)[i];
}
// Bresenham role split: block b -> role B (smaller side, interleaved) or A.
__device__ __forceinline__ bool split_role(int b, int nA, int nB, int* idx) {
    long long t = (long long)nA + nB;
    int before = (int)(((long long)b * nB) / t);
    int after  = (int)(((long long)(b + 1) * nB) / t);
    if (after > before) { *idx = before; return true; }
    *idx = b - before; return false;
}

// ---------------- dtype sniffer --------------------------------------------
__global__ void sniff_k(const u16* __restrict__ probe, int* __restrict__ flag) {
    int t = threadIdx.x;           // 64 threads
    u16 v = probe[2 * t];
    int ex = (v >> 7) & 0xFF;
    int sane = (ex == 0) || (ex >= 0x70 && ex <= 0x8A);
    unsigned long long m = __ballot(sane != 0);
    if (t == 0) *flag = (__popcll(m) >= 48) ? 1 : 0;
}

// ============ prep_k: convert-to-fp16 (x8 vectorized) ∥ bucket histograms ===
// Segment 2 (W_Q) is written TRANSPOSED into wqt[c*128+k] so the gemm can read
// B-fragments directly from global through L1 (32 KB = exactly L1-sized).
__global__ __launch_bounds__(256) void prep_k(
    const void* __restrict__ s1, u16* __restrict__ d1, int n1,
    const void* __restrict__ s2, u16* __restrict__ wqt, int n2,
    const void* __restrict__ s3, u16* __restrict__ d3, int n3,
    const int* __restrict__ flagp, int convBlocks,
    const int* __restrict__ head, int Ee, int nBktE, int* __restrict__ cntE, int nE,
    const int* __restrict__ u_idx, int Ei, int nBktU, int* __restrict__ cntU, int nU) {
    __shared__ int h[1024];
    int idx;
    if (!split_role(blockIdx.x, convBlocks, 2 * NBLK, &idx)) {
        // ---- convert role: 8 elements/thread (all segment sizes % 8 == 0) ----
        int i = (idx * 256 + threadIdx.x) * 8;
        int isBf = *flagp;
        const void* s; u16* d; bool transp = false;
        if (i < n1) { s = s1; d = d1; }
        else {
            i -= n1;
            if (i < n2) { s = s2; d = wqt; transp = true; }
            else {
                i -= n2;
                if (i >= n3) return;
                s = s3; d = d3;
            }
        }
        float v[8];
        if (isBf) {
            u32x4 t = *(const u32x4*)((const u16*)s + i);
            #pragma unroll
            for (int k = 0; k < 4; ++k) {
                v[2 * k]     = bf2f((u16)(t[k] & 0xFFFF));
                v[2 * k + 1] = bf2f((u16)(t[k] >> 16));
            }
        } else {
            float4 f0 = ((const float4*)((const float*)s + i))[0];
            float4 f1 = ((const float4*)((const float*)s + i))[1];
            v[0] = f0.x; v[1] = f0.y; v[2] = f0.z; v[3] = f0.w;
            v[4] = f1.x; v[5] = f1.y; v[6] = f1.z; v[7] = f1.w;
        }
        if (transp) {
            int k = i >> 7, c0 = i & 127;    // 8 consecutive cols of row k
            #pragma unroll
            for (int t = 0; t < 8; ++t) d[(c0 + t) * 128 + k] = f2h(v[t]);
        } else {
            u32x4 o;
            #pragma unroll
            for (int k = 0; k < 4; ++k) o[k] = packh2(v[2 * k], v[2 * k + 1]);
            *(u32x4*)(d + i) = o;
        }
        return;
    }
    // ---- bin_count role ----
    int blk = idx;
    const int* keys; int n, nBkt, nDst; int* cnt;
    if (blk < NBLK) { keys = head;  n = Ee; nBkt = nBktE; cnt = cntE; nDst = nE; }
    else { blk -= NBLK; keys = u_idx; n = Ei; nBkt = nBktU; cnt = cntU; nDst = nU; }
    for (int i = threadIdx.x; i < nBkt; i += 256) h[i] = 0;
    __syncthreads();
    int chunk = (n + NBLK - 1) / NBLK;
    int s = blk * chunk, e = min(s + chunk, n);
    for (int i = s + threadIdx.x; i < e; i += 256) {
        int k = min(max(keys[i], 0), nDst - 1);
        atomicAdd(&h[k >> BSH], 1);
    }
    __syncthreads();
    for (int b = threadIdx.x; b < nBkt; b += 256) cnt[b * NBLK + blk] = h[b];
}

// ---- in-place exclusive scan of cntE (block 0) / cntU (block 1) ------------
__global__ __launch_bounds__(1024) void bin_scan_k(int* __restrict__ cntE, int lenE,
                                                   int* __restrict__ cntU, int lenU) {
    __shared__ int wsum[16];
    int* buf = blockIdx.x ? cntU : cntE;
    int len  = blockIdx.x ? lenU : lenE;
    int t = threadIdx.x, lane = t & 63, wv = t >> 6;
    int per = (len + 1023) / 1024;
    int base = t * per;
    int sum = 0;
    for (int i = 0; i < per; ++i) {
        int idx = base + i;
        if (idx < len) sum += buf[idx];
    }
    int x = sum;
    #pragma unroll
    for (int o = 1; o < 64; o <<= 1) { int y = __shfl_up(x, o); if (lane >= o) x += y; }
    if (lane == 63) wsum[wv] = x;
    __syncthreads();
    if (wv == 0) {
        int v = (lane < 16) ? wsum[lane] : 0;
        int xx = v;
        #pragma unroll
        for (int o = 1; o < 16; o <<= 1) { int y = __shfl_up(xx, o); if (lane >= o) xx += y; }
        if (lane < 16) wsum[lane] = xx - v;      // exclusive wave offsets
    }
    __syncthreads();
    int excl = wsum[wv] + (x - sum);
    for (int i = 0; i < per; ++i) {
        int idx = base + i;
        if (idx < len) { int v = buf[idx]; buf[idx] = excl; excl += v; }
    }
}

// ============ work_k: LDS-free MFMA gemm blocks ∥ edge-binning blocks =======
// gemm reads B-fragments from global WQ^T (L1-resident, 32 KB); no LDS, no
// barrier. Kernel LDS = 4 KB cursor array -> 8 blocks/CU for BOTH roles
// (R6 lesson: fused roles pay max LDS of all roles; keep footprints small).
#define GEMM_ROWS 64

__global__ __launch_bounds__(256) void work_k(
    const u16* __restrict__ E, const u16* __restrict__ WQT,
    u16* __restrict__ P, int nRows, int gemmBlocks, int scatBlocks,
    const int* __restrict__ head, const int* __restrict__ tail,
    const int* __restrict__ etyp, int Ee, int nBktE, const int* __restrict__ cntE,
    int2* __restrict__ binE, int nE, int nEnt,
    const int* __restrict__ u_idx, const int* __restrict__ i_idx,
    const void* __restrict__ iw, int Ei, int nBktU, const int* __restrict__ cntU,
    int2* __restrict__ binU, int nU, const int* __restrict__ flagp) {
    __shared__ int cur[1024];            // 4 KB (scatter-role cursors)
    int idx;
    if (!split_role(blockIdx.x, gemmBlocks, scatBlocks, &idx)) {
        // ---- gemm role: P = E @ W_Q (fp16 in/out, fp32 acc), LDS-free ----
        int t = threadIdx.x;
        int wave = t >> 6, lane = t & 63;
        int m = lane & 15, quad = lane >> 4;
        int row0 = idx * GEMM_ROWS + wave * 16;
        int rowA = min(row0 + m, nRows - 1);
        const u16* erow = E + (size_t)rowA * D;
        f16x8 afrag[4];
        #pragma unroll
        for (int ks = 0; ks < 4; ++ks)
            afrag[ks] = *(const f16x8*)(erow + ks * 32 + quad * 8);
        #pragma unroll
        for (int ct = 0; ct < 8; ++ct) {
            f32x4 acc = {0.f, 0.f, 0.f, 0.f};
            const u16* wcol = WQT + (ct * 16 + m) * D + quad * 8;
            #pragma unroll
            for (int ks = 0; ks < 4; ++ks) {
                f16x8 bfrag = *(const f16x8*)(wcol + ks * 32);
                acc = __builtin_amdgcn_mfma_f32_16x16x32_f16(afrag[ks], bfrag, acc, 0, 0, 0);
            }
            #pragma unroll
            for (int reg = 0; reg < 4; ++reg) {
                int r = row0 + quad * 4 + reg;
                if (r < nRows) P[(size_t)r * D + ct * 16 + m] = f2h(acc[reg]);
            }
        }
        return;
    }
    // ---- bin_scatter role: block-private contiguous runs (write-amp ~1) ----
    int blk = idx;
    if (blk < NBLK) {
        for (int b = threadIdx.x; b < nBktE; b += 256) cur[b] = cntE[b * NBLK + blk];
        __syncthreads();
        int chunk = (Ee + NBLK - 1) / NBLK;
        int s = blk * chunk, e = min(s + chunk, Ee);
        for (int i = s + threadIdx.x; i < e; i += 256) {
            int h  = min(max(head[i], 0), nE - 1);
            int tl = min(max(tail[i], 0), nEnt - 1);
            int rt = min(max(etyp[i] - 1, 0), 9);
            int p = atomicAdd(&cur[h >> BSH], 1);
            binE[p] = make_int2(h, tl | (rt << 24));
        }
    } else {
        blk -= NBLK;
        for (int b = threadIdx.x; b < nBktU; b += 256) cur[b] = cntU[b * NBLK + blk];
        __syncthreads();
        int isBf = *flagp;
        int chunk = (Ei + NBLK - 1) / NBLK;
        int s = blk * chunk, e = min(s + chunk, Ei);
        for (int i = s + threadIdx.x; i < e; i += 256) {
            int u  = min(max(u_idx[i], 0), nU - 1);
            int it = min(min(max(i_idx[i], 0), nEnt - 1), (1 << 22) - 1);
            float w = ldIn(iw, i, isBf);
            int p = atomicAdd(&cur[u >> BSH], 1);
            binU[p] = make_int2(it | ((u & ((1 << BSH) - 1)) << 22), __float_as_int(w));
        }
    }
}

// ---- one block per 128-dst bucket: exact CSR + fine scatter ---------------
// Generic over BSH<=10: hist[1024] zero-padded, full-width scan is correct.
__global__ __launch_bounds__(1024) void csr_finalize_k(
    const int2* __restrict__ binE, const int* __restrict__ cntE, int nBktE,
    int Ee, int nE, int* __restrict__ e_off, int* __restrict__ e_pack,
    const int2* __restrict__ binU, const int* __restrict__ cntU, int nBktU,
    int Ei, int nU, int* __restrict__ u_off, int2* __restrict__ upay) {
    __shared__ int hist[1024];
    __shared__ int wsum[16];
    int b = blockIdx.x;
    int t = threadIdx.x, lane = t & 63, wv = t >> 6;
    bool isE = b < nBktE;
    const int2* bin; const int* cnt; int nBkt, n, nDst; int* off;
    if (isE) { bin = binE; cnt = cntE; nBkt = nBktE; n = Ee; nDst = nE; off = e_off; }
    else { b -= nBktE; bin = binU; cnt = cntU; nBkt = nBktU; n = Ei; nDst = nU; off = u_off; }
    int bs = cnt[b * NBLK];
    int be = (b + 1 < nBkt) ? cnt[(b + 1) * NBLK] : n;
    int d0 = b << BSH;
    int dCount = min(1 << BSH, nDst - d0);
    hist[t] = 0;
    __syncthreads();
    for (int i = bs + t; i < be; i += 1024) {
        int2 v = bin[i];
        int loc = isE ? (v.x - d0) : (int)(((u32)v.x) >> 22);
        atomicAdd(&hist[loc], 1);
    }
    __syncthreads();
    int v = hist[t];
    int x = v;
    #pragma unroll
    for (int o = 1; o < 64; o <<= 1) { int y = __shfl_up(x, o); if (lane >= o) x += y; }
    if (lane == 63) wsum[wv] = x;
    __syncthreads();
    if (wv == 0) {
        int vv = (lane < 16) ? wsum[lane] : 0;
        int xx = vv;
        #pragma unroll
        for (int o = 1; o < 16; o <<= 1) { int y = __shfl_up(xx, o); if (lane >= o) xx += y; }
        if (lane < 16) wsum[lane] = xx - vv;
    }
    __syncthreads();
    int excl = wsum[wv] + (x - v);
    if (t < dCount) off[d0 + t] = bs + excl;
    if (b == nBkt - 1 && t == 0) off[nDst] = n;  // sentinel
    hist[t] = bs + excl;                         // reuse as scatter cursor
    __syncthreads();
    for (int i = bs + t; i < be; i += 1024) {
        int2 v2 = bin[i];
        int loc = isE ? (v2.x - d0) : (int)(((u32)v2.x) >> 22);
        int p = atomicAdd(&hist[loc], 1);
        if (isE) e_pack[p] = v2.y;
        else     upay[p] = make_int2(v2.x & ((1 << 22) - 1), v2.y);
    }
}

// ============ agg_k: entity attention blocks ∥ user aggregation blocks ======
// Entity: one wave per entity, 4 edges in flight (slot es = lane>>4, sub-lane
// g = lane&15 holds dims [8g..8g+7]); fp16 packed math (pk_mul + fdot2).
// Softmax shift-free (|s| << 80). Cross-slot merge: 2 shfl_xor steps.
// [R8 lesson: 8-wide regressed — VGPR 48 halved occupancy and 8-slot groups
//  waste ~40% slots at mean degree 10. 4-wide/1-deep is the equilibrium.]
__global__ __launch_bounds__(256) void agg_k(
    const u16* __restrict__ P, const u16* __restrict__ eCur,
    const u16* __restrict__ relb, const int* __restrict__ e_off,
    const int* __restrict__ e_pack, void* __restrict__ eOut,
    const u32* __restrict__ e0b, int finalMode, size_t outElemOff,
    int nEnt, int entBlocks, int userBlocks,
    const int* __restrict__ u_off, const int2* __restrict__ upay,
    float* __restrict__ usum, const void* __restrict__ ueRaw,
    void* __restrict__ outU, int nU, const int* __restrict__ flagp) {
    // rel rows padded to 17 uint4: rows land on shifted bank groups
    __shared__ __align__(16) u32 sRel[10 * 68];   // 2.7 KiB fp16 pairs
    int tid = threadIdx.x;
    int lane = tid & 63;
    int es = lane >> 4, g = lane & 15;
    int idx;
    if (!split_role(blockIdx.x, entBlocks, userBlocks, &idx)) {
        // ================= entity role =================
        {
            const u32* R = (const u32*)relb;
            for (int i = tid; i < 640; i += 256)
                sRel[(i >> 6) * 68 + (i & 63)] = R[i];
            __syncthreads();
        }
        int wid = idx * 4 + (tid >> 6);
        if (wid >= nEnt) return;
        const u32x4* P4 = (const u32x4*)P;
        const u32x4* E4 = (const u32x4*)eCur;
        const float SC = 0.125f * 1.44269504f;   // /sqrt(64) folded with log2(e)
        h2t qh[4];
        {
            u32x4 qa = P4[(size_t)wid * 16 + g];
            #pragma unroll
            for (int k = 0; k < 4; ++k) qh[k] = u2h2(qa[k]);
        }
        float l = 0.f, a[8];
        #pragma unroll
        for (int k = 0; k < 8; ++k) a[k] = 0.f;
        int s = e_off[wid], e = e_off[wid + 1];
        for (int j0 = s; j0 < e; j0 += 64) {
            int B = min(64, e - j0);
            int pk = (lane < B) ? e_pack[j0 + lane] : 0;
            int pv = __shfl(pk, es);
            size_t off = (size_t)(pv & 0xFFFFFF) * 16 + g;
            u32x4 ptv = P4[off];
            u32x4 evv = E4[off];
            for (int j = 0; j < B; j += 4) {
                u32x4 cpt = ptv, cev = evv;
                int cpv = pv;
                bool act = (j + es) < B;
                if (j + 4 < B) {                 // prefetch next edge group
                    pv = __shfl(pk, j + 4 + es);
                    off = (size_t)(pv & 0xFFFFFF) * 16 + g;
                    ptv = P4[off];
                    evv = E4[off];
                }
                int rt = (int)((u32)cpv >> 24);  // clamped to [0,9] at build
                u32x4 crr = *(const u32x4*)(sRel + rt * 68 + g * 4);
                float prod = 0.f;
                float2 vf[4];
                #pragma unroll
                for (int k = 0; k < 4; ++k) {
                    h2t rr = u2h2(crr[k]);
                    h2t qr = qh[k] * rr;                          // v_pk_mul_f16
                    prod = __builtin_amdgcn_fdot2(qr, u2h2(cpt[k]), prod, false);
                    h2t vr = u2h2(cev[k]) * rr;                   // v_pk_mul_f16
                    vf[k] = h2f2(h22u(vr));
                }
                #pragma unroll
                for (int o = 4; o > 0; o >>= 1) prod += __shfl_xor(prod, o);
                float p = act ? exp2f(prod * SC) : 0.f;
                l += p;
                #pragma unroll
                for (int k = 0; k < 4; ++k) {
                    a[2 * k]     = fmaf(p, vf[k].x, a[2 * k]);
                    a[2 * k + 1] = fmaf(p, vf[k].y, a[2 * k + 1]);
                }
            }
        }
        // merge 4 edge-slot partials (head halves stay separate: g&8 invariant)
        #pragma unroll
        for (int o = 16; o <= 32; o <<= 1) {
            l += __shfl_xor(l, o);
            #pragma unroll
            for (int k = 0; k < 8; ++k) a[k] += __shfl_xor(a[k], o);
        }
        float rl = (l > 0.f) ? 1.f / l : 0.f;
        float w8[8];
        float ss = 0.f;
        #pragma unroll
        for (int k = 0; k < 8; ++k) {
            w8[k] = a[k] * rl;
            ss = fmaf(w8[k], w8[k], ss);
        }
        #pragma unroll
        for (int o = 8; o > 0; o >>= 1) ss += __shfl_xor(ss, o);
        float inv = 1.f / fmaxf(sqrtf(ss), 1e-12f);
        #pragma unroll
        for (int k = 0; k < 8; ++k) w8[k] *= inv;
        if (lane >= 16) return;                  // groups identical; group 0 stores
        if (finalMode) {
            int isBf = *flagp;
            const float k3 = 1.0f / 3.0f;
            float r[8];
            u32x4 t0 = ((const u32x4*)e0b)[(size_t)wid * 16 + g];   // eeb (fp16)
            u32x4 t1 = E4[(size_t)wid * 16 + g];                    // eL1 (fp16)
            #pragma unroll
            for (int k = 0; k < 4; ++k) {
                float2 f0 = h2f2(t0[k]);
                float2 f1 = h2f2(t1[k]);
                r[2 * k]     = (f0.x + f1.x + w8[2 * k]) * k3;
                r[2 * k + 1] = (f0.y + f1.y + w8[2 * k + 1]) * k3;
            }
            size_t be = outElemOff + (size_t)wid * 128 + (size_t)g * 8;
            if (isBf) {
                u32x4 o;
                o[0] = (u32)f2bf(r[0]) | ((u32)f2bf(r[1]) << 16);
                o[1] = (u32)f2bf(r[2]) | ((u32)f2bf(r[3]) << 16);
                o[2] = (u32)f2bf(r[4]) | ((u32)f2bf(r[5]) << 16);
                o[3] = (u32)f2bf(r[6]) | ((u32)f2bf(r[7]) << 16);
                *(u32x4*)((u16*)eOut + be) = o;
            } else {
                *(float4*)((float*)eOut + be)     = make_float4(r[0], r[1], r[2], r[3]);
                *(float4*)((float*)eOut + be + 4) = make_float4(r[4], r[5], r[6], r[7]);
            }
        } else {
            u32x4 o;
            o[0] = packh2(w8[0], w8[1]); o[1] = packh2(w8[2], w8[3]);
            o[2] = packh2(w8[4], w8[5]); o[3] = packh2(w8[6], w8[7]);
            ((u32x4*)eOut)[(size_t)wid * 16 + g] = o;
        }
        return;
    }
    // ================= user role =================
    int wid = idx * 4 + (tid >> 6);
    if (wid >= nU) return;
    const u32x4* E4 = (const u32x4*)eCur;
    float a[8];
    #pragma unroll
    for (int k = 0; k < 8; ++k) a[k] = 0.f;
    int s = u_off[wid], e = u_off[wid + 1];
    for (int j0 = s; j0 < e; j0 += 64) {
        int B = min(64, e - j0);
        int2 pw = make_int2(0, 0);
        if (lane < B) pw = upay[j0 + lane];
        int it = pw.x;
        float wv = __int_as_float(pw.y);     // 0 bits -> 0.0f for lanes >= B
        int i0 = __shfl(it, es);
        float w0 = __shfl(wv, es);
        u32x4 ev0 = E4[(size_t)i0 * 16 + g];
        u32x4 ev1 = ev0;
        float w1 = 0.f;
        if (B > 4) {
            int i1 = __shfl(it, 4 + es);
            w1 = __shfl(wv, 4 + es);
            ev1 = E4[(size_t)i1 * 16 + g];
        }
        for (int j = 0; j < B; j += 4) {
            u32x4 cur = ev0; float wc = w0;
            ev0 = ev1; w0 = w1;
            if (j + 8 < B) {                 // keep 2 iterations in flight
                int nx = __shfl(it, j + 8 + es);
                w1 = __shfl(wv, j + 8 + es);
                ev1 = E4[(size_t)nx * 16 + g];
            }
            #pragma unroll
            for (int k = 0; k < 4; ++k) {
                float2 f = h2f2(cur[k]);
                a[2 * k]     = fmaf(wc, f.x, a[2 * k]);
                a[2 * k + 1] = fmaf(wc, f.y, a[2 * k + 1]);
            }
        }
    }
    #pragma unroll
    for (int o = 16; o <= 32; o <<= 1) {
        #pragma unroll
        for (int k = 0; k < 8; ++k) a[k] += __shfl_xor(a[k], o);
    }
    if (lane >= 16) return;
    size_t base = (size_t)wid * 128 + (size_t)g * 8;
    if (finalMode) {
        int isBf = *flagp;
        const float k3 = 1.0f / 3.0f;
        float4 u0 = ((const float4*)usum)[(size_t)wid * 32 + 2 * g];
        float4 u1 = ((const float4*)usum)[(size_t)wid * 32 + 2 * g + 1];
        float r[8];
        if (isBf) {
            u32x4 t = *(const u32x4*)((const u16*)ueRaw + base);
            #pragma unroll
            for (int k = 0; k < 4; ++k) {
                u32 v = t[k];
                r[2 * k]     = bf2f((u16)(v & 0xFFFF));
                r[2 * k + 1] = bf2f((u16)(v >> 16));
            }
        } else {
            float4 f0 = *(const float4*)((const float*)ueRaw + base);
            float4 f1 = *(const float4*)((const float*)ueRaw + base + 4);
            r[0] = f0.x; r[1] = f0.y; r[2] = f0.z; r[3] = f0.w;
            r[4] = f1.x; r[5] = f1.y; r[6] = f1.z; r[7] = f1.w;
        }
        float o0 = (r[0] + u0.x + a[0]) * k3;
        float o1 = (r[1] + u0.y + a[1]) * k3;
        float o2 = (r[2] + u0.z + a[2]) * k3;
        float o3 = (r[3] + u0.w + a[3]) * k3;
        float o4 = (r[4] + u1.x + a[4]) * k3;
        float o5 = (r[5] + u1.y + a[5]) * k3;
        float o6 = (r[6] + u1.z + a[6]) * k3;
        float o7 = (r[7] + u1.w + a[7]) * k3;
        if (isBf) {
            u32x4 o;
            o[0] = (u32)f2bf(o0) | ((u32)f2bf(o1) << 16);
            o[1] = (u32)f2bf(o2) | ((u32)f2bf(o3) << 16);
            o[2] = (u32)f2bf(o4) | ((u32)f2bf(o5) << 16);
            o[3] = (u32)f2bf(o6) | ((u32)f2bf(o7) << 16);
            *(u32x4*)((u16*)outU + base) = o;
        } else {
            *(float4*)((float*)outU + base)     = make_float4(o0, o1, o2, o3);
            *(float4*)((float*)outU + base + 4) = make_float4(o4, o5, o6, o7);
        }
    } else {
        ((float4*)usum)[(size_t)wid * 32 + 2 * g]     = make_float4(a[0], a[1], a[2], a[3]);
        ((float4*)usum)[(size_t)wid * 32 + 2 * g + 1] = make_float4(a[4], a[5], a[6], a[7]);
    }
}

extern "C" void kernel_launch(void* const* d_in, const int* in_sizes, int n_in,
                              void* d_out, int out_size, void* d_ws, size_t ws_size,
                              hipStream_t stream) {
    const void* ue  = d_in[1];              // user_emb      [nU,128]
    const void* ee  = d_in[2];              // entity_emb    [nE,128]
    const int*  itr = (const int*)d_in[3];  // inter_edge    [2,Ei]
    const void* iw  = d_in[4];              // inter_edge_w  [Ei]
    const int*  eix = (const int*)d_in[5];  // edge_index    [2,Ee]
    const int*  ety = (const int*)d_in[6];  // edge_type     [Ee]
    const void* rel = d_in[7];              // relation_emb  [10,128]
    const void* wq  = d_in[8];              // W_Q           [128,128]

    const int nU = in_sizes[1] / D;
    const int nE = in_sizes[2] / D;
    const int Ei = in_sizes[4];
    const int Ee = in_sizes[6];
    const int nRel = in_sizes[7] / D;   // 10

    const int* u_idx = itr;            // inter_edge[0] (dest users)
    const int* i_idx = itr + Ei;       // inter_edge[1] (src entities)
    const int* head  = eix;            // edge_index[0] (dest entities)
    const int* tail  = eix + Ee;       // edge_index[1] (src entities)

    const int nBktE = (nE + (1 << BSH) - 1) >> BSH;   // 469 for nE=60000
    const int nBktU = (nU + (1 << BSH) - 1) >> BSH;   // 235 for nU=30000

    char* w = (char*)d_ws;
    auto alloc = [&](size_t bytes) {
        char* p = w;
        w += (bytes + 255) & ~(size_t)255;
        return p;
    };
    int*   flag  = (int*)alloc(256);
    int*  e_off  = (int*)alloc((size_t)(nE + 1) * 4);
    int*  u_off  = (int*)alloc((size_t)(nU + 1) * 4);
    int*  e_pack = (int*)alloc((size_t)Ee * 4);
    int2* upay   = (int2*)alloc((size_t)Ei * 8);
    int*  cntE   = (int*)alloc((size_t)nBktE * NBLK * 4);
    int*  cntU   = (int*)alloc((size_t)nBktU * NBLK * 4);
    u16*  wqt    = (u16*)alloc((size_t)D * D * 2);   // W_Q transposed (fp16)
    u16*  relb   = (u16*)alloc((size_t)nRel * D * 2);
    u16*  eeb    = (u16*)alloc((size_t)nE * D * 2);
    u16*  eL1    = (u16*)alloc((size_t)nE * D * 2);
    u16*  P      = (u16*)alloc((size_t)nE * D * 2);
    float* usum  = (float*)alloc((size_t)nU * D * 4);

    // binned edge buffers: alias usum (dead until agg-L1; binE/binU dead after
    // csr_finalize). NOT P — gemm writes P concurrently with bin_scatter.
    int2* binE; int2* binU;
    {
        size_t need = (size_t)(Ee + Ei) * 8;
        if (need <= (size_t)nU * D * 4) {
            binE = (int2*)usum;
            binU = (int2*)((char*)usum + (size_t)Ee * 8);
        } else {
            binE = (int2*)alloc((size_t)Ee * 8);
            binU = (int2*)alloc((size_t)Ei * 8);
        }
    }

    if ((size_t)(w - (char*)d_ws) > ws_size) {
        // Workspace too small. Output stays harness-zeroed.
        return;
    }

    sniff_k<<<1, 64, 0, stream>>>((const u16*)ue, flag);

    const int n1 = nE * D, n2 = D * D, n3 = nRel * D;
    const int convBlocks = ((n1 + n2 + n3) / 8 + 255) / 256;   // all n_i % 8 == 0
    const int entBlocks  = (nE + 3) / 4;
    const int userBlocks = (nU + 3) / 4;
    const int gemmBlocks = (nE + GEMM_ROWS - 1) / GEMM_ROWS;

    // ---- K1: convert (x8; WQ transposed) ∥ bucket histogram ----
    prep_k<<<convBlocks + 2 * NBLK, 256, 0, stream>>>(
        ee, eeb, n1, wq, wqt, n2, rel, relb, n3, flag, convBlocks,
        head, Ee, nBktE, cntE, nE, u_idx, Ei, nBktU, cntU, nU);
    // ---- K2: scan bucket counters ----
    bin_scan_k<<<2, 1024, 0, stream>>>(cntE, nBktE * NBLK, cntU, nBktU * NBLK);
    // ---- K3: gemm L1 (LDS-free) ∥ edge binning ----
    work_k<<<gemmBlocks + 2 * NBLK, 256, 0, stream>>>(
        eeb, wqt, P, nE, gemmBlocks, 2 * NBLK,
        head, tail, ety, Ee, nBktE, cntE, binE, nE, nE,
        u_idx, i_idx, iw, Ei, nBktU, cntU, binU, nU, flag);
    // ---- K4: exact CSR per 128-dst bucket (704 blocks, full fill) ----
    csr_finalize_k<<<nBktE + nBktU, 1024, 0, stream>>>(binE, cntE, nBktE, Ee, nE,
                                                       e_off, e_pack,
                                                       binU, cntU, nBktU, Ei, nU,
                                                       u_off, upay);
    // ---- K5: layer-1 entity ∥ user aggregation ----
    agg_k<<<entBlocks + userBlocks, 256, 0, stream>>>(
        P, eeb, relb, e_off, e_pack, eL1, nullptr, 0, 0, nE, entBlocks, userBlocks,
        u_off, upay, usum, nullptr, nullptr, nU, flag);
    // ---- K6: gemm L2 only ----
    work_k<<<gemmBlocks, 256, 0, stream>>>(
        eL1, wqt, P, nE, gemmBlocks, 0,
        head, tail, ety, Ee, nBktE, cntE, binE, nE, nE,
        u_idx, i_idx, iw, Ei, nBktU, cntU, binU, nU, flag);
    // ---- K7: layer-2 aggregation with fused mean epilogue into d_out ----
    agg_k<<<entBlocks + userBlocks, 256, 0, stream>>>(
        P, eL1, relb, e_off, e_pack, d_out, (const u32*)eeb, 1,
        (size_t)nU * D, nE, entBlocks, userBlocks,
        u_off, upay, usum, ue, d_out, nU, flag);
}

// Round 11
// 371.250 us; speedup vs baseline: 1.2798x; 1.2798x over previous
//
#include <hip/hip_runtime.h>
#include <hip/hip_bf16.h>
#include <hip/hip_fp16.h>

#define D 128
#define BSH 7                  // CSR bucket shift: 128 destinations per bucket
#define NBLK 128               // binning blocks per side
typedef unsigned short u16;
typedef unsigned int u32;
typedef __attribute__((ext_vector_type(4))) unsigned int u32x4;
typedef _Float16 f16;
typedef __attribute__((ext_vector_type(2))) _Float16 h2t;
typedef __attribute__((ext_vector_type(8))) _Float16 f16x8;
typedef __attribute__((ext_vector_type(4))) float f32x4;

__device__ __forceinline__ float bf2f(u16 u) {
    return __uint_as_float(((u32)u) << 16);
}
__device__ __forceinline__ u16 f2bf(float f) {
    union { float f; u32 u; } a; a.f = f;
    u32 r = (a.u + 0x7FFF + ((a.u >> 16) & 1)) >> 16;   // RNE
    return (u16)r;
}
// fp16 helpers (internal canonical dtype — packed math + dot2 on CDNA4)
__device__ __forceinline__ u16 f2h(float f) {
    union { f16 h; u16 u; } c; c.h = (f16)f; return c.u;
}
__device__ __forceinline__ h2t u2h2(u32 v) {
    union { u32 u; h2t h; } c; c.u = v; return c.h;
}
__device__ __forceinline__ u32 h22u(h2t h) {
    union { h2t h; u32 u; } c; c.h = h; return c.u;
}
__device__ __forceinline__ float2 h2f2(u32 v) {
    h2t h = u2h2(v);
    return make_float2((float)h[0], (float)h[1]);
}
__device__ __forceinline__ u32 packh2(float a, float b) {
    union { h2t h; u32 u; } c; c.h[0] = (f16)a; c.h[1] = (f16)b; return c.u;
}
// flag-dependent raw-input access (epilogue / prep only)
__device__ __forceinline__ float ldIn(const void* p, size_t i, int isBf) {
    return isBf ? bf2f(((const u16*)p)[i]) : ((const float*)p)[i];
}
// Bresenham role split: block b -> role B (smaller side, interleaved) or A.
__device__ __forceinline__ bool split_role(int b, int nA, int nB, int* idx) {
    long long t = (long long)nA + nB;
    int before = (int)(((long long)b * nB) / t);
    int after  = (int)(((long long)(b + 1) * nB) / t);
    if (after > before) { *idx = before; return true; }
    *idx = b - before; return false;
}

// ---------------- dtype sniffer --------------------------------------------
__global__ void sniff_k(const u16* __restrict__ probe, int* __restrict__ flag) {
    int t = threadIdx.x;           // 64 threads
    u16 v = probe[2 * t];
    int ex = (v >> 7) & 0xFF;
    int sane = (ex == 0) || (ex >= 0x70 && ex <= 0x8A);
    unsigned long long m = __ballot(sane != 0);
    if (t == 0) *flag = (__popcll(m) >= 48) ? 1 : 0;
}

// ============ prep_k: convert-to-fp16 (x8 vectorized) ∥ bucket histograms ===
// Segment 2 (W_Q) is written TRANSPOSED into wqt[c*128+k] so the gemm can read
// B-fragments directly from global through L1 (32 KB = exactly L1-sized).
__global__ __launch_bounds__(256) void prep_k(
    const void* __restrict__ s1, u16* __restrict__ d1, int n1,
    const void* __restrict__ s2, u16* __restrict__ wqt, int n2,
    const void* __restrict__ s3, u16* __restrict__ d3, int n3,
    const int* __restrict__ flagp, int convBlocks,
    const int* __restrict__ head, int Ee, int nBktE, int* __restrict__ cntE, int nE,
    const int* __restrict__ u_idx, int Ei, int nBktU, int* __restrict__ cntU, int nU) {
    __shared__ int h[1024];
    int idx;
    if (!split_role(blockIdx.x, convBlocks, 2 * NBLK, &idx)) {
        // ---- convert role: 8 elements/thread (all segment sizes % 8 == 0) ----
        int i = (idx * 256 + threadIdx.x) * 8;
        int isBf = *flagp;
        const void* s; u16* d; bool transp = false;
        if (i < n1) { s = s1; d = d1; }
        else {
            i -= n1;
            if (i < n2) { s = s2; d = wqt; transp = true; }
            else {
                i -= n2;
                if (i >= n3) return;
                s = s3; d = d3;
            }
        }
        float v[8];
        if (isBf) {
            u32x4 t = *(const u32x4*)((const u16*)s + i);
            #pragma unroll
            for (int k = 0; k < 4; ++k) {
                v[2 * k]     = bf2f((u16)(t[k] & 0xFFFF));
                v[2 * k + 1] = bf2f((u16)(t[k] >> 16));
            }
        } else {
            float4 f0 = ((const float4*)((const float*)s + i))[0];
            float4 f1 = ((const float4*)((const float*)s + i))[1];
            v[0] = f0.x; v[1] = f0.y; v[2] = f0.z; v[3] = f0.w;
            v[4] = f1.x; v[5] = f1.y; v[6] = f1.z; v[7] = f1.w;
        }
        if (transp) {
            int k = i >> 7, c0 = i & 127;    // 8 consecutive cols of row k
            #pragma unroll
            for (int t = 0; t < 8; ++t) d[(c0 + t) * 128 + k] = f2h(v[t]);
        } else {
            u32x4 o;
            #pragma unroll
            for (int k = 0; k < 4; ++k) o[k] = packh2(v[2 * k], v[2 * k + 1]);
            *(u32x4*)(d + i) = o;
        }
        return;
    }
    // ---- bin_count role ----
    int blk = idx;
    const int* keys; int n, nBkt, nDst; int* cnt;
    if (blk < NBLK) { keys = head;  n = Ee; nBkt = nBktE; cnt = cntE; nDst = nE; }
    else { blk -= NBLK; keys = u_idx; n = Ei; nBkt = nBktU; cnt = cntU; nDst = nU; }
    for (int i = threadIdx.x; i < nBkt; i += 256) h[i] = 0;
    __syncthreads();
    int chunk = (n + NBLK - 1) / NBLK;
    int s = blk * chunk, e = min(s + chunk, n);
    for (int i = s + threadIdx.x; i < e; i += 256) {
        int k = min(max(keys[i], 0), nDst - 1);
        atomicAdd(&h[k >> BSH], 1);
    }
    __syncthreads();
    for (int b = threadIdx.x; b < nBkt; b += 256) cnt[b * NBLK + blk] = h[b];
}

// ---- factored scan, stage 1: per-bucket local exclusive scan + totals ------
// One block (128 thr = 2 waves) per bucket: scans its 128 per-block counts in
// place and writes the bucket total. 704 blocks -> fully parallel.
// [R10 lesson: the flat 60k-element 2-block scan was a 114 µs serial-latency
//  chain. Exploit the [bucket][block] factorization instead.]
__global__ __launch_bounds__(128) void bin_scan1_k(
    int* __restrict__ cntE, int nBktE, int* __restrict__ totE,
    int* __restrict__ cntU, int* __restrict__ totU) {
    __shared__ int w0tot;
    int b = blockIdx.x;
    int* cnt; int* tot; int bb;
    if (b < nBktE) { cnt = cntE; tot = totE; bb = b; }
    else { cnt = cntU; tot = totU; bb = b - nBktE; }
    int t = threadIdx.x, lane = t & 63, wv = t >> 6;
    int v = cnt[bb * NBLK + t];
    int x = v;
    #pragma unroll
    for (int o = 1; o < 64; o <<= 1) { int y = __shfl_up(x, o); if (lane >= o) x += y; }
    if (wv == 0 && lane == 63) w0tot = x;
    __syncthreads();
    int off = wv ? w0tot : 0;
    cnt[bb * NBLK + t] = off + x - v;        // exclusive within bucket
    if (t == 127) tot[bb] = off + x;         // bucket total
}
// ---- stage 2: exclusive scan of bucket totals (len <= ~500, per=1) ---------
__global__ __launch_bounds__(1024) void bin_scan_k(int* __restrict__ bufE, int lenE,
                                                   int* __restrict__ bufU, int lenU) {
    __shared__ int wsum[16];
    int* buf = blockIdx.x ? bufU : bufE;
    int len  = blockIdx.x ? lenU : lenE;
    int t = threadIdx.x, lane = t & 63, wv = t >> 6;
    int per = (len + 1023) / 1024;
    int base = t * per;
    int sum = 0;
    for (int i = 0; i < per; ++i) {
        int idx = base + i;
        if (idx < len) sum += buf[idx];
    }
    int x = sum;
    #pragma unroll
    for (int o = 1; o < 64; o <<= 1) { int y = __shfl_up(x, o); if (lane >= o) x += y; }
    if (lane == 63) wsum[wv] = x;
    __syncthreads();
    if (wv == 0) {
        int v = (lane < 16) ? wsum[lane] : 0;
        int xx = v;
        #pragma unroll
        for (int o = 1; o < 16; o <<= 1) { int y = __shfl_up(xx, o); if (lane >= o) xx += y; }
        if (lane < 16) wsum[lane] = xx - v;      // exclusive wave offsets
    }
    __syncthreads();
    int excl = wsum[wv] + (x - sum);
    for (int i = 0; i < per; ++i) {
        int idx = base + i;
        if (idx < len) { int v = buf[idx]; buf[idx] = excl; excl += v; }
    }
}

// ============ work_k: LDS-free MFMA gemm blocks ∥ edge-binning blocks =======
// gemm reads B-fragments from global WQ^T (L1-resident, 32 KB); no LDS, no
// barrier. Kernel LDS = 4 KB cursor array -> high occupancy for BOTH roles
// (R6 lesson: fused roles pay max LDS of all roles; keep footprints small).
#define GEMM_ROWS 64

__global__ __launch_bounds__(256) void work_k(
    const u16* __restrict__ E, const u16* __restrict__ WQT,
    u16* __restrict__ P, int nRows, int gemmBlocks, int scatBlocks,
    const int* __restrict__ head, const int* __restrict__ tail,
    const int* __restrict__ etyp, int Ee, int nBktE, const int* __restrict__ cntE,
    const int* __restrict__ totE, int2* __restrict__ binE, int nE, int nEnt,
    const int* __restrict__ u_idx, const int* __restrict__ i_idx,
    const void* __restrict__ iw, int Ei, int nBktU, const int* __restrict__ cntU,
    const int* __restrict__ totU, int2* __restrict__ binU, int nU,
    const int* __restrict__ flagp) {
    __shared__ int cur[1024];            // 4 KB (scatter-role cursors)
    int idx;
    if (!split_role(blockIdx.x, gemmBlocks, scatBlocks, &idx)) {
        // ---- gemm role: P = E @ W_Q (fp16 in/out, fp32 acc), LDS-free ----
        int t = threadIdx.x;
        int wave = t >> 6, lane = t & 63;
        int m = lane & 15, quad = lane >> 4;
        int row0 = idx * GEMM_ROWS + wave * 16;
        int rowA = min(row0 + m, nRows - 1);
        const u16* erow = E + (size_t)rowA * D;
        f16x8 afrag[4];
        #pragma unroll
        for (int ks = 0; ks < 4; ++ks)
            afrag[ks] = *(const f16x8*)(erow + ks * 32 + quad * 8);
        #pragma unroll
        for (int ct = 0; ct < 8; ++ct) {
            f32x4 acc = {0.f, 0.f, 0.f, 0.f};
            const u16* wcol = WQT + (ct * 16 + m) * D + quad * 8;
            #pragma unroll
            for (int ks = 0; ks < 4; ++ks) {
                f16x8 bfrag = *(const f16x8*)(wcol + ks * 32);
                acc = __builtin_amdgcn_mfma_f32_16x16x32_f16(afrag[ks], bfrag, acc, 0, 0, 0);
            }
            #pragma unroll
            for (int reg = 0; reg < 4; ++reg) {
                int r = row0 + quad * 4 + reg;
                if (r < nRows) P[(size_t)r * D + ct * 16 + m] = f2h(acc[reg]);
            }
        }
        return;
    }
    // ---- bin_scatter role: block-private contiguous runs (write-amp ~1) ----
    // cursor = bucket base (tot) + this block's exclusive offset within bucket
    int blk = idx;
    if (blk < NBLK) {
        for (int b = threadIdx.x; b < nBktE; b += 256)
            cur[b] = totE[b] + cntE[b * NBLK + blk];
        __syncthreads();
        int chunk = (Ee + NBLK - 1) / NBLK;
        int s = blk * chunk, e = min(s + chunk, Ee);
        for (int i = s + threadIdx.x; i < e; i += 256) {
            int h  = min(max(head[i], 0), nE - 1);
            int tl = min(max(tail[i], 0), nEnt - 1);
            int rt = min(max(etyp[i] - 1, 0), 9);
            int p = atomicAdd(&cur[h >> BSH], 1);
            binE[p] = make_int2(h, tl | (rt << 24));
        }
    } else {
        blk -= NBLK;
        for (int b = threadIdx.x; b < nBktU; b += 256)
            cur[b] = totU[b] + cntU[b * NBLK + blk];
        __syncthreads();
        int isBf = *flagp;
        int chunk = (Ei + NBLK - 1) / NBLK;
        int s = blk * chunk, e = min(s + chunk, Ei);
        for (int i = s + threadIdx.x; i < e; i += 256) {
            int u  = min(max(u_idx[i], 0), nU - 1);
            int it = min(min(max(i_idx[i], 0), nEnt - 1), (1 << 22) - 1);
            float w = ldIn(iw, i, isBf);
            int p = atomicAdd(&cur[u >> BSH], 1);
            binU[p] = make_int2(it | ((u & ((1 << BSH) - 1)) << 22), __float_as_int(w));
        }
    }
}

// ---- one block per 128-dst bucket: exact CSR + fine scatter ---------------
// Generic over BSH<=10: hist[1024] zero-padded, full-width scan is correct.
// Bucket range comes from the tot arrays (bs = tot[b], be = tot[b+1]).
__global__ __launch_bounds__(1024) void csr_finalize_k(
    const int2* __restrict__ binE, const int* __restrict__ totE, int nBktE,
    int Ee, int nE, int* __restrict__ e_off, int* __restrict__ e_pack,
    const int2* __restrict__ binU, const int* __restrict__ totU, int nBktU,
    int Ei, int nU, int* __restrict__ u_off, int2* __restrict__ upay) {
    __shared__ int hist[1024];
    __shared__ int wsum[16];
    int b = blockIdx.x;
    int t = threadIdx.x, lane = t & 63, wv = t >> 6;
    bool isE = b < nBktE;
    const int2* bin; const int* tot; int nBkt, n, nDst; int* off;
    if (isE) { bin = binE; tot = totE; nBkt = nBktE; n = Ee; nDst = nE; off = e_off; }
    else { b -= nBktE; bin = binU; tot = totU; nBkt = nBktU; n = Ei; nDst = nU; off = u_off; }
    int bs = tot[b];
    int be = (b + 1 < nBkt) ? tot[b + 1] : n;
    int d0 = b << BSH;
    int dCount = min(1 << BSH, nDst - d0);
    hist[t] = 0;
    __syncthreads();
    for (int i = bs + t; i < be; i += 1024) {
        int2 v = bin[i];
        int loc = isE ? (v.x - d0) : (int)(((u32)v.x) >> 22);
        atomicAdd(&hist[loc], 1);
    }
    __syncthreads();
    int v = hist[t];
    int x = v;
    #pragma unroll
    for (int o = 1; o < 64; o <<= 1) { int y = __shfl_up(x, o); if (lane >= o) x += y; }
    if (lane == 63) wsum[wv] = x;
    __syncthreads();
    if (wv == 0) {
        int vv = (lane < 16) ? wsum[lane] : 0;
        int xx = vv;
        #pragma unroll
        for (int o = 1; o < 16; o <<= 1) { int y = __shfl_up(xx, o); if (lane >= o) xx += y; }
        if (lane < 16) wsum[lane] = xx - vv;
    }
    __syncthreads();
    int excl = wsum[wv] + (x - v);
    if (t < dCount) off[d0 + t] = bs + excl;
    if (b == nBkt - 1 && t == 0) off[nDst] = n;  // sentinel
    hist[t] = bs + excl;                         // reuse as scatter cursor
    __syncthreads();
    for (int i = bs + t; i < be; i += 1024) {
        int2 v2 = bin[i];
        int loc = isE ? (v2.x - d0) : (int)(((u32)v2.x) >> 22);
        int p = atomicAdd(&hist[loc], 1);
        if (isE) e_pack[p] = v2.y;
        else     upay[p] = make_int2(v2.x & ((1 << 22) - 1), v2.y);
    }
}

// ============ agg_k: entity attention blocks ∥ user aggregation blocks ======
// Entity: one wave per entity, 4 edges in flight (slot es = lane>>4, sub-lane
// g = lane&15 holds dims [8g..8g+7]); fp16 packed math (pk_mul + fdot2).
// Softmax shift-free (|s| << 80). Cross-slot merge: 2 shfl_xor steps.
// [R8 lesson: 8-wide regressed — VGPR 48 halved occupancy and 8-slot groups
//  waste ~40% slots at mean degree 10. 4-wide/1-deep is the equilibrium.]
__global__ __launch_bounds__(256) void agg_k(
    const u16* __restrict__ P, const u16* __restrict__ eCur,
    const u16* __restrict__ relb, const int* __restrict__ e_off,
    const int* __restrict__ e_pack, void* __restrict__ eOut,
    const u32* __restrict__ e0b, int finalMode, size_t outElemOff,
    int nEnt, int entBlocks, int userBlocks,
    const int* __restrict__ u_off, const int2* __restrict__ upay,
    float* __restrict__ usum, const void* __restrict__ ueRaw,
    void* __restrict__ outU, int nU, const int* __restrict__ flagp) {
    // rel rows padded to 17 uint4: rows land on shifted bank groups
    __shared__ __align__(16) u32 sRel[10 * 68];   // 2.7 KiB fp16 pairs
    int tid = threadIdx.x;
    int lane = tid & 63;
    int es = lane >> 4, g = lane & 15;
    int idx;
    if (!split_role(blockIdx.x, entBlocks, userBlocks, &idx)) {
        // ================= entity role =================
        {
            const u32* R = (const u32*)relb;
            for (int i = tid; i < 640; i += 256)
                sRel[(i >> 6) * 68 + (i & 63)] = R[i];
            __syncthreads();
        }
        int wid = idx * 4 + (tid >> 6);
        if (wid >= nEnt) return;
        const u32x4* P4 = (const u32x4*)P;
        const u32x4* E4 = (const u32x4*)eCur;
        const float SC = 0.125f * 1.44269504f;   // /sqrt(64) folded with log2(e)
        h2t qh[4];
        {
            u32x4 qa = P4[(size_t)wid * 16 + g];
            #pragma unroll
            for (int k = 0; k < 4; ++k) qh[k] = u2h2(qa[k]);
        }
        float l = 0.f, a[8];
        #pragma unroll
        for (int k = 0; k < 8; ++k) a[k] = 0.f;
        int s = e_off[wid], e = e_off[wid + 1];
        for (int j0 = s; j0 < e; j0 += 64) {
            int B = min(64, e - j0);
            int pk = (lane < B) ? e_pack[j0 + lane] : 0;
            int pv = __shfl(pk, es);
            size_t off = (size_t)(pv & 0xFFFFFF) * 16 + g;
            u32x4 ptv = P4[off];
            u32x4 evv = E4[off];
            for (int j = 0; j < B; j += 4) {
                u32x4 cpt = ptv, cev = evv;
                int cpv = pv;
                bool act = (j + es) < B;
                if (j + 4 < B) {                 // prefetch next edge group
                    pv = __shfl(pk, j + 4 + es);
                    off = (size_t)(pv & 0xFFFFFF) * 16 + g;
                    ptv = P4[off];
                    evv = E4[off];
                }
                int rt = (int)((u32)cpv >> 24);  // clamped to [0,9] at build
                u32x4 crr = *(const u32x4*)(sRel + rt * 68 + g * 4);
                float prod = 0.f;
                float2 vf[4];
                #pragma unroll
                for (int k = 0; k < 4; ++k) {
                    h2t rr = u2h2(crr[k]);
                    h2t qr = qh[k] * rr;                          // v_pk_mul_f16
                    prod = __builtin_amdgcn_fdot2(qr, u2h2(cpt[k]), prod, false);
                    h2t vr = u2h2(cev[k]) * rr;                   // v_pk_mul_f16
                    vf[k] = h2f2(h22u(vr));
                }
                #pragma unroll
                for (int o = 4; o > 0; o >>= 1) prod += __shfl_xor(prod, o);
                float p = act ? exp2f(prod * SC) : 0.f;
                l += p;
                #pragma unroll
                for (int k = 0; k < 4; ++k) {
                    a[2 * k]     = fmaf(p, vf[k].x, a[2 * k]);
                    a[2 * k + 1] = fmaf(p, vf[k].y, a[2 * k + 1]);
                }
            }
        }
        // merge 4 edge-slot partials (head halves stay separate: g&8 invariant)
        #pragma unroll
        for (int o = 16; o <= 32; o <<= 1) {
            l += __shfl_xor(l, o);
            #pragma unroll
            for (int k = 0; k < 8; ++k) a[k] += __shfl_xor(a[k], o);
        }
        float rl = (l > 0.f) ? 1.f / l : 0.f;
        float w8[8];
        float ss = 0.f;
        #pragma unroll
        for (int k = 0; k < 8; ++k) {
            w8[k] = a[k] * rl;
            ss = fmaf(w8[k], w8[k], ss);
        }
        #pragma unroll
        for (int o = 8; o > 0; o >>= 1) ss += __shfl_xor(ss, o);
        float inv = 1.f / fmaxf(sqrtf(ss), 1e-12f);
        #pragma unroll
        for (int k = 0; k < 8; ++k) w8[k] *= inv;
        if (lane >= 16) return;                  // groups identical; group 0 stores
        if (finalMode) {
            int isBf = *flagp;
            const float k3 = 1.0f / 3.0f;
            float r[8];
            u32x4 t0 = ((const u32x4*)e0b)[(size_t)wid * 16 + g];   // eeb (fp16)
            u32x4 t1 = E4[(size_t)wid * 16 + g];                    // eL1 (fp16)
            #pragma unroll
            for (int k = 0; k < 4; ++k) {
                float2 f0 = h2f2(t0[k]);
                float2 f1 = h2f2(t1[k]);
                r[2 * k]     = (f0.x + f1.x + w8[2 * k]) * k3;
                r[2 * k + 1] = (f0.y + f1.y + w8[2 * k + 1]) * k3;
            }
            size_t be = outElemOff + (size_t)wid * 128 + (size_t)g * 8;
            if (isBf) {
                u32x4 o;
                o[0] = (u32)f2bf(r[0]) | ((u32)f2bf(r[1]) << 16);
                o[1] = (u32)f2bf(r[2]) | ((u32)f2bf(r[3]) << 16);
                o[2] = (u32)f2bf(r[4]) | ((u32)f2bf(r[5]) << 16);
                o[3] = (u32)f2bf(r[6]) | ((u32)f2bf(r[7]) << 16);
                *(u32x4*)((u16*)eOut + be) = o;
            } else {
                *(float4*)((float*)eOut + be)     = make_float4(r[0], r[1], r[2], r[3]);
                *(float4*)((float*)eOut + be + 4) = make_float4(r[4], r[5], r[6], r[7]);
            }
        } else {
            u32x4 o;
            o[0] = packh2(w8[0], w8[1]); o[1] = packh2(w8[2], w8[3]);
            o[2] = packh2(w8[4], w8[5]); o[3] = packh2(w8[6], w8[7]);
            ((u32x4*)eOut)[(size_t)wid * 16 + g] = o;
        }
        return;
    }
    // ================= user role =================
    int wid = idx * 4 + (tid >> 6);
    if (wid >= nU) return;
    const u32x4* E4 = (const u32x4*)eCur;
    float a[8];
    #pragma unroll
    for (int k = 0; k < 8; ++k) a[k] = 0.f;
    int s = u_off[wid], e = u_off[wid + 1];
    for (int j0 = s; j0 < e; j0 += 64) {
        int B = min(64, e - j0);
        int2 pw = make_int2(0, 0);
        if (lane < B) pw = upay[j0 + lane];
        int it = pw.x;
        float wv = __int_as_float(pw.y);     // 0 bits -> 0.0f for lanes >= B
        int i0 = __shfl(it, es);
        float w0 = __shfl(wv, es);
        u32x4 ev0 = E4[(size_t)i0 * 16 + g];
        u32x4 ev1 = ev0;
        float w1 = 0.f;
        if (B > 4) {
            int i1 = __shfl(it, 4 + es);
            w1 = __shfl(wv, 4 + es);
            ev1 = E4[(size_t)i1 * 16 + g];
        }
        for (int j = 0; j < B; j += 4) {
            u32x4 cur = ev0; float wc = w0;
            ev0 = ev1; w0 = w1;
            if (j + 8 < B) {                 // keep 2 iterations in flight
                int nx = __shfl(it, j + 8 + es);
                w1 = __shfl(wv, j + 8 + es);
                ev1 = E4[(size_t)nx * 16 + g];
            }
            #pragma unroll
            for (int k = 0; k < 4; ++k) {
                float2 f = h2f2(cur[k]);
                a[2 * k]     = fmaf(wc, f.x, a[2 * k]);
                a[2 * k + 1] = fmaf(wc, f.y, a[2 * k + 1]);
            }
        }
    }
    #pragma unroll
    for (int o = 16; o <= 32; o <<= 1) {
        #pragma unroll
        for (int k = 0; k < 8; ++k) a[k] += __shfl_xor(a[k], o);
    }
    if (lane >= 16) return;
    size_t base = (size_t)wid * 128 + (size_t)g * 8;
    if (finalMode) {
        int isBf = *flagp;
        const float k3 = 1.0f / 3.0f;
        float4 u0 = ((const float4*)usum)[(size_t)wid * 32 + 2 * g];
        float4 u1 = ((const float4*)usum)[(size_t)wid * 32 + 2 * g + 1];
        float r[8];
        if (isBf) {
            u32x4 t = *(const u32x4*)((const u16*)ueRaw + base);
            #pragma unroll
            for (int k = 0; k < 4; ++k) {
                u32 v = t[k];
                r[2 * k]     = bf2f((u16)(v & 0xFFFF));
                r[2 * k + 1] = bf2f((u16)(v >> 16));
            }
        } else {
            float4 f0 = *(const float4*)((const float*)ueRaw + base);
            float4 f1 = *(const float4*)((const float*)ueRaw + base + 4);
            r[0] = f0.x; r[1] = f0.y; r[2] = f0.z; r[3] = f0.w;
            r[4] = f1.x; r[5] = f1.y; r[6] = f1.z; r[7] = f1.w;
        }
        float o0 = (r[0] + u0.x + a[0]) * k3;
        float o1 = (r[1] + u0.y + a[1]) * k3;
        float o2 = (r[2] + u0.z + a[2]) * k3;
        float o3 = (r[3] + u0.w + a[3]) * k3;
        float o4 = (r[4] + u1.x + a[4]) * k3;
        float o5 = (r[5] + u1.y + a[5]) * k3;
        float o6 = (r[6] + u1.z + a[6]) * k3;
        float o7 = (r[7] + u1.w + a[7]) * k3;
        if (isBf) {
            u32x4 o;
            o[0] = (u32)f2bf(o0) | ((u32)f2bf(o1) << 16);
            o[1] = (u32)f2bf(o2) | ((u32)f2bf(o3) << 16);
            o[2] = (u32)f2bf(o4) | ((u32)f2bf(o5) << 16);
            o[3] = (u32)f2bf(o6) | ((u32)f2bf(o7) << 16);
            *(u32x4*)((u16*)outU + base) = o;
        } else {
            *(float4*)((float*)outU + base)     = make_float4(o0, o1, o2, o3);
            *(float4*)((float*)outU + base + 4) = make_float4(o4, o5, o6, o7);
        }
    } else {
        ((float4*)usum)[(size_t)wid * 32 + 2 * g]     = make_float4(a[0], a[1], a[2], a[3]);
        ((float4*)usum)[(size_t)wid * 32 + 2 * g + 1] = make_float4(a[4], a[5], a[6], a[7]);
    }
}

extern "C" void kernel_launch(void* const* d_in, const int* in_sizes, int n_in,
                              void* d_out, int out_size, void* d_ws, size_t ws_size,
                              hipStream_t stream) {
    const void* ue  = d_in[1];              // user_emb      [nU,128]
    const void* ee  = d_in[2];              // entity_emb    [nE,128]
    const int*  itr = (const int*)d_in[3];  // inter_edge    [2,Ei]
    const void* iw  = d_in[4];              // inter_edge_w  [Ei]
    const int*  eix = (const int*)d_in[5];  // edge_index    [2,Ee]
    const int*  ety = (const int*)d_in[6];  // edge_type     [Ee]
    const void* rel = d_in[7];              // relation_emb  [10,128]
    const void* wq  = d_in[8];              // W_Q           [128,128]

    const int nU = in_sizes[1] / D;
    const int nE = in_sizes[2] / D;
    const int Ei = in_sizes[4];
    const int Ee = in_sizes[6];
    const int nRel = in_sizes[7] / D;   // 10

    const int* u_idx = itr;            // inter_edge[0] (dest users)
    const int* i_idx = itr + Ei;       // inter_edge[1] (src entities)
    const int* head  = eix;            // edge_index[0] (dest entities)
    const int* tail  = eix + Ee;       // edge_index[1] (src entities)

    const int nBktE = (nE + (1 << BSH) - 1) >> BSH;   // 469 for nE=60000
    const int nBktU = (nU + (1 << BSH) - 1) >> BSH;   // 235 for nU=30000

    char* w = (char*)d_ws;
    auto alloc = [&](size_t bytes) {
        char* p = w;
        w += (bytes + 255) & ~(size_t)255;
        return p;
    };
    int*   flag  = (int*)alloc(256);
    int*  e_off  = (int*)alloc((size_t)(nE + 1) * 4);
    int*  u_off  = (int*)alloc((size_t)(nU + 1) * 4);
    int*  e_pack = (int*)alloc((size_t)Ee * 4);
    int2* upay   = (int2*)alloc((size_t)Ei * 8);
    int*  cntE   = (int*)alloc((size_t)nBktE * NBLK * 4);
    int*  cntU   = (int*)alloc((size_t)nBktU * NBLK * 4);
    int*  totE   = (int*)alloc((size_t)nBktE * 4);
    int*  totU   = (int*)alloc((size_t)nBktU * 4);
    u16*  wqt    = (u16*)alloc((size_t)D * D * 2);   // W_Q transposed (fp16)
    u16*  relb   = (u16*)alloc((size_t)nRel * D * 2);
    u16*  eeb    = (u16*)alloc((size_t)nE * D * 2);
    u16*  eL1    = (u16*)alloc((size_t)nE * D * 2);
    u16*  P      = (u16*)alloc((size_t)nE * D * 2);
    float* usum  = (float*)alloc((size_t)nU * D * 4);

    // binned edge buffers: alias usum (dead until agg-L1; binE/binU dead after
    // csr_finalize). NOT P — gemm writes P concurrently with bin_scatter.
    int2* binE; int2* binU;
    {
        size_t need = (size_t)(Ee + Ei) * 8;
        if (need <= (size_t)nU * D * 4) {
            binE = (int2*)usum;
            binU = (int2*)((char*)usum + (size_t)Ee * 8);
        } else {
            binE = (int2*)alloc((size_t)Ee * 8);
            binU = (int2*)alloc((size_t)Ei * 8);
        }
    }

    if ((size_t)(w - (char*)d_ws) > ws_size) {
        // Workspace too small. Output stays harness-zeroed.
        return;
    }

    sniff_k<<<1, 64, 0, stream>>>((const u16*)ue, flag);

    const int n1 = nE * D, n2 = D * D, n3 = nRel * D;
    const int convBlocks = ((n1 + n2 + n3) / 8 + 255) / 256;   // all n_i % 8 == 0
    const int entBlocks  = (nE + 3) / 4;
    const int userBlocks = (nU + 3) / 4;
    const int gemmBlocks = (nE + GEMM_ROWS - 1) / GEMM_ROWS;

    // ---- K1: convert (x8; WQ transposed) ∥ bucket histogram ----
    prep_k<<<convBlocks + 2 * NBLK, 256, 0, stream>>>(
        ee, eeb, n1, wq, wqt, n2, rel, relb, n3, flag, convBlocks,
        head, Ee, nBktE, cntE, nE, u_idx, Ei, nBktU, cntU, nU);
    // ---- K2a: per-bucket local scan + totals (704 blocks, parallel) ----
    bin_scan1_k<<<nBktE + nBktU, 128, 0, stream>>>(cntE, nBktE, totE, cntU, totU);
    // ---- K2b: scan bucket totals (len 469 / 235, per=1) ----
    bin_scan_k<<<2, 1024, 0, stream>>>(totE, nBktE, totU, nBktU);
    // ---- K3: gemm L1 (LDS-free) ∥ edge binning ----
    work_k<<<gemmBlocks + 2 * NBLK, 256, 0, stream>>>(
        eeb, wqt, P, nE, gemmBlocks, 2 * NBLK,
        head, tail, ety, Ee, nBktE, cntE, totE, binE, nE, nE,
        u_idx, i_idx, iw, Ei, nBktU, cntU, totU, binU, nU, flag);
    // ---- K4: exact CSR per 128-dst bucket (704 blocks, full fill) ----
    csr_finalize_k<<<nBktE + nBktU, 1024, 0, stream>>>(binE, totE, nBktE, Ee, nE,
                                                       e_off, e_pack,
                                                       binU, totU, nBktU, Ei, nU,
                                                       u_off, upay);
    // ---- K5: layer-1 entity ∥ user aggregation ----
    agg_k<<<entBlocks + userBlocks, 256, 0, stream>>>(
        P, eeb, relb, e_off, e_pack, eL1, nullptr, 0, 0, nE, entBlocks, userBlocks,
        u_off, upay, usum, nullptr, nullptr, nU, flag);
    // ---- K6: gemm L2 only ----
    work_k<<<gemmBlocks, 256, 0, stream>>>(
        eL1, wqt, P, nE, gemmBlocks, 0,
        head, tail, ety, Ee, nBktE, cntE, totE, binE, nE, nE,
        u_idx, i_idx, iw, Ei, nBktU, cntU, totU, binU, nU, flag);
    // ---- K7: layer-2 aggregation with fused mean epilogue into d_out ----
    agg_k<<<entBlocks + userBlocks, 256, 0, stream>>>(
        P, eL1, relb, e_off, e_pack, d_out, (const u32*)eeb, 1,
        (size_t)nU * D, nE, entBlocks, userBlocks,
        u_off, upay, usum, ue, d_out, nU, flag);
}

// Round 12
// 360.187 us; speedup vs baseline: 1.3191x; 1.0307x over previous
//
#include <hip/hip_runtime.h>
#include <hip/hip_bf16.h>
#include <hip/hip_fp16.h>

#define D 128
#define BSH 10                 // CSR bucket shift: 1024 destinations per bucket
#define NBLK 128               // binning blocks per side
typedef unsigned short u16;
typedef unsigned int u32;
typedef __attribute__((ext_vector_type(4))) unsigned int u32x4;
typedef _Float16 f16;
typedef __attribute__((ext_vector_type(2))) _Float16 h2t;
typedef __attribute__((ext_vector_type(8))) _Float16 f16x8;
typedef __attribute__((ext_vector_type(4))) float f32x4;

__device__ __forceinline__ float bf2f(u16 u) {
    return __uint_as_float(((u32)u) << 16);
}
__device__ __forceinline__ u16 f2bf(float f) {
    union { float f; u32 u; } a; a.f = f;
    u32 r = (a.u + 0x7FFF + ((a.u >> 16) & 1)) >> 16;   // RNE
    return (u16)r;
}
// fp16 helpers (internal canonical dtype — packed math + dot2 on CDNA4)
__device__ __forceinline__ u16 f2h(float f) {
    union { f16 h; u16 u; } c; c.h = (f16)f; return c.u;
}
__device__ __forceinline__ h2t u2h2(u32 v) {
    union { u32 u; h2t h; } c; c.u = v; return c.h;
}
__device__ __forceinline__ u32 h22u(h2t h) {
    union { h2t h; u32 u; } c; c.h = h; return c.u;
}
__device__ __forceinline__ float2 h2f2(u32 v) {
    h2t h = u2h2(v);
    return make_float2((float)h[0], (float)h[1]);
}
__device__ __forceinline__ u32 packh2(float a, float b) {
    union { h2t h; u32 u; } c; c.h[0] = (f16)a; c.h[1] = (f16)b; return c.u;
}
// flag-dependent raw-input access (epilogue / prep only)
__device__ __forceinline__ float ldIn(const void* p, size_t i, int isBf) {
    return isBf ? bf2f(((const u16*)p)[i]) : ((const float*)p)[i];
}
// Bresenham role split: block b -> role B (smaller side, interleaved) or A.
__device__ __forceinline__ bool split_role(int b, int nA, int nB, int* idx) {
    long long t = (long long)nA + nB;
    int before = (int)(((long long)b * nB) / t);
    int after  = (int)(((long long)(b + 1) * nB) / t);
    if (after > before) { *idx = before; return true; }
    *idx = b - before; return false;
}

// ---------------- dtype sniffer --------------------------------------------
__global__ void sniff_k(const u16* __restrict__ probe, int* __restrict__ flag) {
    int t = threadIdx.x;           // 64 threads
    u16 v = probe[2 * t];
    int ex = (v >> 7) & 0xFF;
    int sane = (ex == 0) || (ex >= 0x70 && ex <= 0x8A);
    unsigned long long m = __ballot(sane != 0);
    if (t == 0) *flag = (__popcll(m) >= 48) ? 1 : 0;
}

// ============ prep_k: convert-to-fp16 (x8 vectorized) ∥ bucket histograms ===
__global__ __launch_bounds__(256) void prep_k(
    const void* __restrict__ s1, u16* __restrict__ d1, int n1,
    const void* __restrict__ s2, u16* __restrict__ d2, int n2,
    const void* __restrict__ s3, u16* __restrict__ d3, int n3,
    const int* __restrict__ flagp, int convBlocks,
    const int* __restrict__ head, int Ee, int nBktE, int* __restrict__ cntE, int nE,
    const int* __restrict__ u_idx, int Ei, int nBktU, int* __restrict__ cntU, int nU) {
    __shared__ int h[1024];
    int idx;
    if (!split_role(blockIdx.x, convBlocks, 2 * NBLK, &idx)) {
        // ---- convert role: 8 elements/thread (all segment sizes % 8 == 0) ----
        int i = (idx * 256 + threadIdx.x) * 8;
        int isBf = *flagp;
        const void* s; u16* d;
        if (i < n1) { s = s1; d = d1; }
        else {
            i -= n1;
            if (i < n2) { s = s2; d = d2; }
            else {
                i -= n2;
                if (i >= n3) return;
                s = s3; d = d3;
            }
        }
        u32x4 o;
        if (isBf) {
            u32x4 v = *(const u32x4*)((const u16*)s + i);
            #pragma unroll
            for (int k = 0; k < 4; ++k)
                o[k] = packh2(bf2f((u16)(v[k] & 0xFFFF)), bf2f((u16)(v[k] >> 16)));
        } else {
            float4 f0 = ((const float4*)((const float*)s + i))[0];
            float4 f1 = ((const float4*)((const float*)s + i))[1];
            o[0] = packh2(f0.x, f0.y); o[1] = packh2(f0.z, f0.w);
            o[2] = packh2(f1.x, f1.y); o[3] = packh2(f1.z, f1.w);
        }
        *(u32x4*)(d + i) = o;
        return;
    }
    // ---- bin_count role ----
    int blk = idx;
    const int* keys; int n, nBkt, nDst; int* cnt;
    if (blk < NBLK) { keys = head;  n = Ee; nBkt = nBktE; cnt = cntE; nDst = nE; }
    else { blk -= NBLK; keys = u_idx; n = Ei; nBkt = nBktU; cnt = cntU; nDst = nU; }
    for (int i = threadIdx.x; i < nBkt; i += 256) h[i] = 0;
    __syncthreads();
    int chunk = (n + NBLK - 1) / NBLK;
    int s = blk * chunk, e = min(s + chunk, n);
    for (int i = s + threadIdx.x; i < e; i += 256) {
        int k = min(max(keys[i], 0), nDst - 1);
        atomicAdd(&h[k >> BSH], 1);
    }
    __syncthreads();
    for (int b = threadIdx.x; b < nBkt; b += 256) cnt[b * NBLK + blk] = h[b];
}

// ---- factored scan, stage 1: per-bucket local exclusive scan + totals ------
// One block (128 thr = 2 waves) per bucket: scans its 128 per-block counts in
// place and writes the bucket total. Fully parallel at any BSH.
// [R10 lesson: a flat serial-chain scan was a 114 µs latency landmine.]
__global__ __launch_bounds__(128) void bin_scan1_k(
    int* __restrict__ cntE, int nBktE, int* __restrict__ totE,
    int* __restrict__ cntU, int* __restrict__ totU) {
    __shared__ int w0tot;
    int b = blockIdx.x;
    int* cnt; int* tot; int bb;
    if (b < nBktE) { cnt = cntE; tot = totE; bb = b; }
    else { cnt = cntU; tot = totU; bb = b - nBktE; }
    int t = threadIdx.x, lane = t & 63, wv = t >> 6;
    int v = cnt[bb * NBLK + t];
    int x = v;
    #pragma unroll
    for (int o = 1; o < 64; o <<= 1) { int y = __shfl_up(x, o); if (lane >= o) x += y; }
    if (wv == 0 && lane == 63) w0tot = x;
    __syncthreads();
    int off = wv ? w0tot : 0;
    cnt[bb * NBLK + t] = off + x - v;        // exclusive within bucket
    if (t == 127) tot[bb] = off + x;         // bucket total
}
// ---- stage 2: exclusive scan of bucket totals (len <= 64, per=1) -----------
__global__ __launch_bounds__(1024) void bin_scan_k(int* __restrict__ bufE, int lenE,
                                                   int* __restrict__ bufU, int lenU) {
    __shared__ int wsum[16];
    int* buf = blockIdx.x ? bufU : bufE;
    int len  = blockIdx.x ? lenU : lenE;
    int t = threadIdx.x, lane = t & 63, wv = t >> 6;
    int per = (len + 1023) / 1024;
    int base = t * per;
    int sum = 0;
    for (int i = 0; i < per; ++i) {
        int idx = base + i;
        if (idx < len) sum += buf[idx];
    }
    int x = sum;
    #pragma unroll
    for (int o = 1; o < 64; o <<= 1) { int y = __shfl_up(x, o); if (lane >= o) x += y; }
    if (lane == 63) wsum[wv] = x;
    __syncthreads();
    if (wv == 0) {
        int v = (lane < 16) ? wsum[lane] : 0;
        int xx = v;
        #pragma unroll
        for (int o = 1; o < 16; o <<= 1) { int y = __shfl_up(xx, o); if (lane >= o) xx += y; }
        if (lane < 16) wsum[lane] = xx - v;      // exclusive wave offsets
    }
    __syncthreads();
    int excl = wsum[wv] + (x - sum);
    for (int i = 0; i < per; ++i) {
        int idx = base + i;
        if (idx < len) { int v = buf[idx]; buf[idx] = excl; excl += v; }
    }
}

// ============ work_k: MFMA gemm blocks ∥ edge-binning blocks ================
// [R11 lesson: LDS-free gemm (WQ^T via L1) regressed — E-row streaming evicts
//  the 32KB WQ^T from the 32KB L1. LDS staging is the right home for W.]
#define GEMM_ROWS 64
#define WT_STRIDE 136   // u16: 68-dword lane stride -> 2-way bank alias (free)

__global__ __launch_bounds__(256) void work_k(
    const u16* __restrict__ E, const u16* __restrict__ WQ,
    u16* __restrict__ P, int nRows, int gemmBlocks, int scatBlocks,
    const int* __restrict__ head, const int* __restrict__ tail,
    const int* __restrict__ etyp, int Ee, int nBktE, const int* __restrict__ cntE,
    const int* __restrict__ totE, int2* __restrict__ binE, int nE, int nEnt,
    const int* __restrict__ u_idx, const int* __restrict__ i_idx,
    const void* __restrict__ iw, int Ei, int nBktU, const int* __restrict__ cntU,
    const int* __restrict__ totU, int2* __restrict__ binU, int nU,
    const int* __restrict__ flagp) {
    __shared__ u16 sWT[D * WT_STRIDE];   // 34 KiB; scatter role reuses as cursors
    int idx;
    if (!split_role(blockIdx.x, gemmBlocks, scatBlocks, &idx)) {
        // ---- gemm role: P = E @ W_Q (fp16 in/out, fp32 acc) ----
        int t = threadIdx.x;
        for (int i = t; i < D * D; i += 256) {
            int k = i >> 7, c = i & 127;     // WQ[k][c] coalesced read
            sWT[c * WT_STRIDE + k] = WQ[i];
        }
        __syncthreads();
        int wave = t >> 6, lane = t & 63;
        int m = lane & 15, quad = lane >> 4;
        int row0 = idx * GEMM_ROWS + wave * 16;
        int rowA = min(row0 + m, nRows - 1);
        const u16* erow = E + (size_t)rowA * D;
        f16x8 afrag[4];
        #pragma unroll
        for (int ks = 0; ks < 4; ++ks)
            afrag[ks] = *(const f16x8*)(erow + ks * 32 + quad * 8);
        #pragma unroll
        for (int ct = 0; ct < 8; ++ct) {
            f32x4 acc = {0.f, 0.f, 0.f, 0.f};
            const u16* wcol = sWT + (ct * 16 + m) * WT_STRIDE + quad * 8;
            #pragma unroll
            for (int ks = 0; ks < 4; ++ks) {
                f16x8 bfrag = *(const f16x8*)(wcol + ks * 32);
                acc = __builtin_amdgcn_mfma_f32_16x16x32_f16(afrag[ks], bfrag, acc, 0, 0, 0);
            }
            #pragma unroll
            for (int reg = 0; reg < 4; ++reg) {
                int r = row0 + quad * 4 + reg;
                if (r < nRows) P[(size_t)r * D + ct * 16 + m] = f2h(acc[reg]);
            }
        }
        return;
    }
    // ---- bin_scatter role: block-private contiguous runs (write-amp ~1) ----
    // cursor = bucket base (tot) + this block's exclusive offset within bucket
    int* cur = (int*)sWT;
    int blk = idx;
    if (blk < NBLK) {
        for (int b = threadIdx.x; b < nBktE; b += 256)
            cur[b] = totE[b] + cntE[b * NBLK + blk];
        __syncthreads();
        int chunk = (Ee + NBLK - 1) / NBLK;
        int s = blk * chunk, e = min(s + chunk, Ee);
        for (int i = s + threadIdx.x; i < e; i += 256) {
            int h  = min(max(head[i], 0), nE - 1);
            int tl = min(max(tail[i], 0), nEnt - 1);
            int rt = min(max(etyp[i] - 1, 0), 9);
            int p = atomicAdd(&cur[h >> BSH], 1);
            binE[p] = make_int2(h, tl | (rt << 24));
        }
    } else {
        blk -= NBLK;
        for (int b = threadIdx.x; b < nBktU; b += 256)
            cur[b] = totU[b] + cntU[b * NBLK + blk];
        __syncthreads();
        int isBf = *flagp;
        int chunk = (Ei + NBLK - 1) / NBLK;
        int s = blk * chunk, e = min(s + chunk, Ei);
        for (int i = s + threadIdx.x; i < e; i += 256) {
            int u  = min(max(u_idx[i], 0), nU - 1);
            int it = min(min(max(i_idx[i], 0), nEnt - 1), (1 << 22) - 1);
            float w = ldIn(iw, i, isBf);
            int p = atomicAdd(&cur[u >> BSH], 1);
            binU[p] = make_int2(it | ((u & ((1 << BSH) - 1)) << 22), __float_as_int(w));
        }
    }
}

// ---- one block per bucket: exact CSR + fine scatter (L2-resident window) ----
__global__ __launch_bounds__(1024) void csr_finalize_k(
    const int2* __restrict__ binE, const int* __restrict__ totE, int nBktE,
    int Ee, int nE, int* __restrict__ e_off, int* __restrict__ e_pack,
    const int2* __restrict__ binU, const int* __restrict__ totU, int nBktU,
    int Ei, int nU, int* __restrict__ u_off, int2* __restrict__ upay) {
    __shared__ int hist[1024];
    __shared__ int wsum[16];
    int b = blockIdx.x;
    int t = threadIdx.x, lane = t & 63, wv = t >> 6;
    bool isE = b < nBktE;
    const int2* bin; const int* tot; int nBkt, n, nDst; int* off;
    if (isE) { bin = binE; tot = totE; nBkt = nBktE; n = Ee; nDst = nE; off = e_off; }
    else { b -= nBktE; bin = binU; tot = totU; nBkt = nBktU; n = Ei; nDst = nU; off = u_off; }
    int bs = tot[b];
    int be = (b + 1 < nBkt) ? tot[b + 1] : n;
    int d0 = b << BSH;
    int dCount = min(1 << BSH, nDst - d0);
    hist[t] = 0;
    __syncthreads();
    for (int i = bs + t; i < be; i += 1024) {
        int2 v = bin[i];
        int loc = isE ? (v.x - d0) : (int)(((u32)v.x) >> 22);
        atomicAdd(&hist[loc], 1);
    }
    __syncthreads();
    int v = hist[t];
    int x = v;
    #pragma unroll
    for (int o = 1; o < 64; o <<= 1) { int y = __shfl_up(x, o); if (lane >= o) x += y; }
    if (lane == 63) wsum[wv] = x;
    __syncthreads();
    if (wv == 0) {
        int vv = (lane < 16) ? wsum[lane] : 0;
        int xx = vv;
        #pragma unroll
        for (int o = 1; o < 16; o <<= 1) { int y = __shfl_up(xx, o); if (lane >= o) xx += y; }
        if (lane < 16) wsum[lane] = xx - vv;
    }
    __syncthreads();
    int excl = wsum[wv] + (x - v);
    if (t < dCount) off[d0 + t] = bs + excl;
    if (b == nBkt - 1 && t == 0) off[nDst] = n;  // sentinel
    hist[t] = bs + excl;                         // reuse as scatter cursor
    __syncthreads();
    for (int i = bs + t; i < be; i += 1024) {
        int2 v2 = bin[i];
        int loc = isE ? (v2.x - d0) : (int)(((u32)v2.x) >> 22);
        int p = atomicAdd(&hist[loc], 1);
        if (isE) e_pack[p] = v2.y;
        else     upay[p] = make_int2(v2.x & ((1 << 22) - 1), v2.y);
    }
}

// ============ agg_k: entity attention blocks ∥ user aggregation blocks ======
// Entity: one wave per entity, 4 edges in flight (slot es = lane>>4, sub-lane
// g = lane&15 holds dims [8g..8g+7]); fp16 packed math (pk_mul + fdot2).
// Softmax shift-free (|s| << 80). Cross-slot merge: 2 shfl_xor steps.
// [R8 lesson: 8-wide regressed — VGPR 48 halved occupancy and 8-slot groups
//  waste ~40% slots at mean degree 10. 4-wide/1-deep is the equilibrium.]
__global__ __launch_bounds__(256) void agg_k(
    const u16* __restrict__ P, const u16* __restrict__ eCur,
    const u16* __restrict__ relb, const int* __restrict__ e_off,
    const int* __restrict__ e_pack, void* __restrict__ eOut,
    const u32* __restrict__ e0b, int finalMode, size_t outElemOff,
    int nEnt, int entBlocks, int userBlocks,
    const int* __restrict__ u_off, const int2* __restrict__ upay,
    float* __restrict__ usum, const void* __restrict__ ueRaw,
    void* __restrict__ outU, int nU, const int* __restrict__ flagp) {
    // rel rows padded to 17 uint4: rows land on shifted bank groups
    __shared__ __align__(16) u32 sRel[10 * 68];   // 2.7 KiB fp16 pairs
    int tid = threadIdx.x;
    int lane = tid & 63;
    int es = lane >> 4, g = lane & 15;
    int idx;
    if (!split_role(blockIdx.x, entBlocks, userBlocks, &idx)) {
        // ================= entity role =================
        {
            const u32* R = (const u32*)relb;
            for (int i = tid; i < 640; i += 256)
                sRel[(i >> 6) * 68 + (i & 63)] = R[i];
            __syncthreads();
        }
        int wid = idx * 4 + (tid >> 6);
        if (wid >= nEnt) return;
        const u32x4* P4 = (const u32x4*)P;
        const u32x4* E4 = (const u32x4*)eCur;
        const float SC = 0.125f * 1.44269504f;   // /sqrt(64) folded with log2(e)
        h2t qh[4];
        {
            u32x4 qa = P4[(size_t)wid * 16 + g];
            #pragma unroll
            for (int k = 0; k < 4; ++k) qh[k] = u2h2(qa[k]);
        }
        float l = 0.f, a[8];
        #pragma unroll
        for (int k = 0; k < 8; ++k) a[k] = 0.f;
        int s = e_off[wid], e = e_off[wid + 1];
        for (int j0 = s; j0 < e; j0 += 64) {
            int B = min(64, e - j0);
            int pk = (lane < B) ? e_pack[j0 + lane] : 0;
            int pv = __shfl(pk, es);
            size_t off = (size_t)(pv & 0xFFFFFF) * 16 + g;
            u32x4 ptv = P4[off];
            u32x4 evv = E4[off];
            for (int j = 0; j < B; j += 4) {
                u32x4 cpt = ptv, cev = evv;
                int cpv = pv;
                bool act = (j + es) < B;
                if (j + 4 < B) {                 // prefetch next edge group
                    pv = __shfl(pk, j + 4 + es);
                    off = (size_t)(pv & 0xFFFFFF) * 16 + g;
                    ptv = P4[off];
                    evv = E4[off];
                }
                int rt = (int)((u32)cpv >> 24);  // clamped to [0,9] at build
                u32x4 crr = *(const u32x4*)(sRel + rt * 68 + g * 4);
                float prod = 0.f;
                float2 vf[4];
                #pragma unroll
                for (int k = 0; k < 4; ++k) {
                    h2t rr = u2h2(crr[k]);
                    h2t qr = qh[k] * rr;                          // v_pk_mul_f16
                    prod = __builtin_amdgcn_fdot2(qr, u2h2(cpt[k]), prod, false);
                    h2t vr = u2h2(cev[k]) * rr;                   // v_pk_mul_f16
                    vf[k] = h2f2(h22u(vr));
                }
                #pragma unroll
                for (int o = 4; o > 0; o >>= 1) prod += __shfl_xor(prod, o);
                float p = act ? exp2f(prod * SC) : 0.f;
                l += p;
                #pragma unroll
                for (int k = 0; k < 4; ++k) {
                    a[2 * k]     = fmaf(p, vf[k].x, a[2 * k]);
                    a[2 * k + 1] = fmaf(p, vf[k].y, a[2 * k + 1]);
                }
            }
        }
        // merge 4 edge-slot partials (head halves stay separate: g&8 invariant)
        #pragma unroll
        for (int o = 16; o <= 32; o <<= 1) {
            l += __shfl_xor(l, o);
            #pragma unroll
            for (int k = 0; k < 8; ++k) a[k] += __shfl_xor(a[k], o);
        }
        float rl = (l > 0.f) ? 1.f / l : 0.f;
        float w8[8];
        float ss = 0.f;
        #pragma unroll
        for (int k = 0; k < 8; ++k) {
            w8[k] = a[k] * rl;
            ss = fmaf(w8[k], w8[k], ss);
        }
        #pragma unroll
        for (int o = 8; o > 0; o >>= 1) ss += __shfl_xor(ss, o);
        float inv = 1.f / fmaxf(sqrtf(ss), 1e-12f);
        #pragma unroll
        for (int k = 0; k < 8; ++k) w8[k] *= inv;
        if (lane >= 16) return;                  // groups identical; group 0 stores
        if (finalMode) {
            int isBf = *flagp;
            const float k3 = 1.0f / 3.0f;
            float r[8];
            u32x4 t0 = ((const u32x4*)e0b)[(size_t)wid * 16 + g];   // eeb (fp16)
            u32x4 t1 = E4[(size_t)wid * 16 + g];                    // eL1 (fp16)
            #pragma unroll
            for (int k = 0; k < 4; ++k) {
                float2 f0 = h2f2(t0[k]);
                float2 f1 = h2f2(t1[k]);
                r[2 * k]     = (f0.x + f1.x + w8[2 * k]) * k3;
                r[2 * k + 1] = (f0.y + f1.y + w8[2 * k + 1]) * k3;
            }
            size_t be = outElemOff + (size_t)wid * 128 + (size_t)g * 8;
            if (isBf) {
                u32x4 o;
                o[0] = (u32)f2bf(r[0]) | ((u32)f2bf(r[1]) << 16);
                o[1] = (u32)f2bf(r[2]) | ((u32)f2bf(r[3]) << 16);
                o[2] = (u32)f2bf(r[4]) | ((u32)f2bf(r[5]) << 16);
                o[3] = (u32)f2bf(r[6]) | ((u32)f2bf(r[7]) << 16);
                *(u32x4*)((u16*)eOut + be) = o;
            } else {
                *(float4*)((float*)eOut + be)     = make_float4(r[0], r[1], r[2], r[3]);
                *(float4*)((float*)eOut + be + 4) = make_float4(r[4], r[5], r[6], r[7]);
            }
        } else {
            u32x4 o;
            o[0] = packh2(w8[0], w8[1]); o[1] = packh2(w8[2], w8[3]);
            o[2] = packh2(w8[4], w8[5]); o[3] = packh2(w8[6], w8[7]);
            ((u32x4*)eOut)[(size_t)wid * 16 + g] = o;
        }
        return;
    }
    // ================= user role =================
    int wid = idx * 4 + (tid >> 6);
    if (wid >= nU) return;
    const u32x4* E4 = (const u32x4*)eCur;
    float a[8];
    #pragma unroll
    for (int k = 0; k < 8; ++k) a[k] = 0.f;
    int s = u_off[wid], e = u_off[wid + 1];
    for (int j0 = s; j0 < e; j0 += 64) {
        int B = min(64, e - j0);
        int2 pw = make_int2(0, 0);
        if (lane < B) pw = upay[j0 + lane];
        int it = pw.x;
        float wv = __int_as_float(pw.y);     // 0 bits -> 0.0f for lanes >= B
        int i0 = __shfl(it, es);
        float w0 = __shfl(wv, es);
        u32x4 ev0 = E4[(size_t)i0 * 16 + g];
        u32x4 ev1 = ev0;
        float w1 = 0.f;
        if (B > 4) {
            int i1 = __shfl(it, 4 + es);
            w1 = __shfl(wv, 4 + es);
            ev1 = E4[(size_t)i1 * 16 + g];
        }
        for (int j = 0; j < B; j += 4) {
            u32x4 cur = ev0; float wc = w0;
            ev0 = ev1; w0 = w1;
            if (j + 8 < B) {                 // keep 2 iterations in flight
                int nx = __shfl(it, j + 8 + es);
                w1 = __shfl(wv, j + 8 + es);
                ev1 = E4[(size_t)nx * 16 + g];
            }
            #pragma unroll
            for (int k = 0; k < 4; ++k) {
                float2 f = h2f2(cur[k]);
                a[2 * k]     = fmaf(wc, f.x, a[2 * k]);
                a[2 * k + 1] = fmaf(wc, f.y, a[2 * k + 1]);
            }
        }
    }
    #pragma unroll
    for (int o = 16; o <= 32; o <<= 1) {
        #pragma unroll
        for (int k = 0; k < 8; ++k) a[k] += __shfl_xor(a[k], o);
    }
    if (lane >= 16) return;
    size_t base = (size_t)wid * 128 + (size_t)g * 8;
    if (finalMode) {
        int isBf = *flagp;
        const float k3 = 1.0f / 3.0f;
        float4 u0 = ((const float4*)usum)[(size_t)wid * 32 + 2 * g];
        float4 u1 = ((const float4*)usum)[(size_t)wid * 32 + 2 * g + 1];
        float r[8];
        if (isBf) {
            u32x4 t = *(const u32x4*)((const u16*)ueRaw + base);
            #pragma unroll
            for (int k = 0; k < 4; ++k) {
                u32 v = t[k];
                r[2 * k]     = bf2f((u16)(v & 0xFFFF));
                r[2 * k + 1] = bf2f((u16)(v >> 16));
            }
        } else {
            float4 f0 = *(const float4*)((const float*)ueRaw + base);
            float4 f1 = *(const float4*)((const float*)ueRaw + base + 4);
            r[0] = f0.x; r[1] = f0.y; r[2] = f0.z; r[3] = f0.w;
            r[4] = f1.x; r[5] = f1.y; r[6] = f1.z; r[7] = f1.w;
        }
        float o0 = (r[0] + u0.x + a[0]) * k3;
        float o1 = (r[1] + u0.y + a[1]) * k3;
        float o2 = (r[2] + u0.z + a[2]) * k3;
        float o3 = (r[3] + u0.w + a[3]) * k3;
        float o4 = (r[4] + u1.x + a[4]) * k3;
        float o5 = (r[5] + u1.y + a[5]) * k3;
        float o6 = (r[6] + u1.z + a[6]) * k3;
        float o7 = (r[7] + u1.w + a[7]) * k3;
        if (isBf) {
            u32x4 o;
            o[0] = (u32)f2bf(o0) | ((u32)f2bf(o1) << 16);
            o[1] = (u32)f2bf(o2) | ((u32)f2bf(o3) << 16);
            o[2] = (u32)f2bf(o4) | ((u32)f2bf(o5) << 16);
            o[3] = (u32)f2bf(o6) | ((u32)f2bf(o7) << 16);
            *(u32x4*)((u16*)outU + base) = o;
        } else {
            *(float4*)((float*)outU + base)     = make_float4(o0, o1, o2, o3);
            *(float4*)((float*)outU + base + 4) = make_float4(o4, o5, o6, o7);
        }
    } else {
        ((float4*)usum)[(size_t)wid * 32 + 2 * g]     = make_float4(a[0], a[1], a[2], a[3]);
        ((float4*)usum)[(size_t)wid * 32 + 2 * g + 1] = make_float4(a[4], a[5], a[6], a[7]);
    }
}

extern "C" void kernel_launch(void* const* d_in, const int* in_sizes, int n_in,
                              void* d_out, int out_size, void* d_ws, size_t ws_size,
                              hipStream_t stream) {
    const void* ue  = d_in[1];              // user_emb      [nU,128]
    const void* ee  = d_in[2];              // entity_emb    [nE,128]
    const int*  itr = (const int*)d_in[3];  // inter_edge    [2,Ei]
    const void* iw  = d_in[4];              // inter_edge_w  [Ei]
    const int*  eix = (const int*)d_in[5];  // edge_index    [2,Ee]
    const int*  ety = (const int*)d_in[6];  // edge_type     [Ee]
    const void* rel = d_in[7];              // relation_emb  [10,128]
    const void* wq  = d_in[8];              // W_Q           [128,128]

    const int nU = in_sizes[1] / D;
    const int nE = in_sizes[2] / D;
    const int Ei = in_sizes[4];
    const int Ee = in_sizes[6];
    const int nRel = in_sizes[7] / D;   // 10

    const int* u_idx = itr;            // inter_edge[0] (dest users)
    const int* i_idx = itr + Ei;       // inter_edge[1] (src entities)
    const int* head  = eix;            // edge_index[0] (dest entities)
    const int* tail  = eix + Ee;       // edge_index[1] (src entities)

    const int nBktE = (nE + (1 << BSH) - 1) >> BSH;   // 59 for nE=60000
    const int nBktU = (nU + (1 << BSH) - 1) >> BSH;   // 30 for nU=30000

    char* w = (char*)d_ws;
    auto alloc = [&](size_t bytes) {
        char* p = w;
        w += (bytes + 255) & ~(size_t)255;
        return p;
    };
    int*   flag  = (int*)alloc(256);
    int*  e_off  = (int*)alloc((size_t)(nE + 1) * 4);
    int*  u_off  = (int*)alloc((size_t)(nU + 1) * 4);
    int*  e_pack = (int*)alloc((size_t)Ee * 4);
    int2* upay   = (int2*)alloc((size_t)Ei * 8);
    int*  cntE   = (int*)alloc((size_t)nBktE * NBLK * 4);
    int*  cntU   = (int*)alloc((size_t)nBktU * NBLK * 4);
    int*  totE   = (int*)alloc((size_t)nBktE * 4);
    int*  totU   = (int*)alloc((size_t)nBktU * 4);
    u16*  wqb    = (u16*)alloc((size_t)D * D * 2);
    u16*  relb   = (u16*)alloc((size_t)nRel * D * 2);
    u16*  eeb    = (u16*)alloc((size_t)nE * D * 2);
    u16*  eL1    = (u16*)alloc((size_t)nE * D * 2);
    u16*  P      = (u16*)alloc((size_t)nE * D * 2);
    float* usum  = (float*)alloc((size_t)nU * D * 4);

    // binned edge buffers: alias usum (dead until agg-L1; binE/binU dead after
    // csr_finalize). NOT P — gemm writes P concurrently with bin_scatter.
    int2* binE; int2* binU;
    {
        size_t need = (size_t)(Ee + Ei) * 8;
        if (need <= (size_t)nU * D * 4) {
            binE = (int2*)usum;
            binU = (int2*)((char*)usum + (size_t)Ee * 8);
        } else {
            binE = (int2*)alloc((size_t)Ee * 8);
            binU = (int2*)alloc((size_t)Ei * 8);
        }
    }

    if ((size_t)(w - (char*)d_ws) > ws_size) {
        // Workspace too small. Output stays harness-zeroed.
        return;
    }

    sniff_k<<<1, 64, 0, stream>>>((const u16*)ue, flag);

    const int n1 = nE * D, n2 = D * D, n3 = nRel * D;
    const int convBlocks = ((n1 + n2 + n3) / 8 + 255) / 256;   // all n_i % 8 == 0
    const int entBlocks  = (nE + 3) / 4;
    const int userBlocks = (nU + 3) / 4;
    const int gemmBlocks = (nE + GEMM_ROWS - 1) / GEMM_ROWS;

    // ---- K1: convert (x8) ∥ bucket histogram ----
    prep_k<<<convBlocks + 2 * NBLK, 256, 0, stream>>>(
        ee, eeb, n1, wq, wqb, n2, rel, relb, n3, flag, convBlocks,
        head, Ee, nBktE, cntE, nE, u_idx, Ei, nBktU, cntU, nU);
    // ---- K2a: per-bucket local scan + totals (89 blocks, parallel) ----
    bin_scan1_k<<<nBktE + nBktU, 128, 0, stream>>>(cntE, nBktE, totE, cntU, totU);
    // ---- K2b: scan bucket totals (len 59 / 30, per=1) ----
    bin_scan_k<<<2, 1024, 0, stream>>>(totE, nBktE, totU, nBktU);
    // ---- K3: gemm L1 ∥ edge binning ----
    work_k<<<gemmBlocks + 2 * NBLK, 256, 0, stream>>>(
        eeb, wqb, P, nE, gemmBlocks, 2 * NBLK,
        head, tail, ety, Ee, nBktE, cntE, totE, binE, nE, nE,
        u_idx, i_idx, iw, Ei, nBktU, cntU, totU, binU, nU, flag);
    // ---- K4: exact CSR per bucket ----
    csr_finalize_k<<<nBktE + nBktU, 1024, 0, stream>>>(binE, totE, nBktE, Ee, nE,
                                                       e_off, e_pack,
                                                       binU, totU, nBktU, Ei, nU,
                                                       u_off, upay);
    // ---- K5: layer-1 entity ∥ user aggregation ----
    agg_k<<<entBlocks + userBlocks, 256, 0, stream>>>(
        P, eeb, relb, e_off, e_pack, eL1, nullptr, 0, 0, nE, entBlocks, userBlocks,
        u_off, upay, usum, nullptr, nullptr, nU, flag);
    // ---- K6: gemm L2 only ----
    work_k<<<gemmBlocks, 256, 0, stream>>>(
        eL1, wqb, P, nE, gemmBlocks, 0,
        head, tail, ety, Ee, nBktE, cntE, totE, binE, nE, nE,
        u_idx, i_idx, iw, Ei, nBktU, cntU, totU, binU, nU, flag);
    // ---- K7: layer-2 aggregation with fused mean epilogue into d_out ----
    agg_k<<<entBlocks + userBlocks, 256, 0, stream>>>(
        P, eL1, relb, e_off, e_pack, d_out, (const u32*)eeb, 1,
        (size_t)nU * D, nE, entBlocks, userBlocks,
        u_off, upay, usum, ue, d_out, nU, flag);
}